// Round 4
// baseline (192.843 us; speedup 1.0000x reference)
//
#include <hip/hip_runtime.h>
#include <hip/hip_bf16.h>
#include <math.h>

typedef __attribute__((ext_vector_type(8))) short bf16x8;
typedef __attribute__((ext_vector_type(8))) unsigned short u16x8;
typedef __attribute__((ext_vector_type(4))) float f32x4;
typedef unsigned short ushort_t;

// Problem: B=4,H=W=128,C=128,F=256,K=9. out = ((bilinear-sample(x,offs)*mod) @ kernel) + bias
// ws layout (bytes):
//   0        : xbf   bf16 [4*128*128*128]          16,777,216
//   16777216 : wt2   bf16 [36][256][32]               589,824   (kcg-major, frag-contiguous)
//   17367040 : wom2  bf16 [36][32][32]                 73,728
//   17440768 : metaw f32x4 [65536*9]                9,437,184   (premult bilinear weights)
//   26877952 : metai int2  [65536*9]                4,718,592   (base elem offset, dy|dx code)

__device__ __forceinline__ ushort_t f2bf(float f) {
    union { float f; unsigned int u; } v; v.f = f;
    unsigned int u = v.u;
    return (ushort_t)((u + 0x7fffu + ((u >> 16) & 1u)) >> 16);
}

__device__ __forceinline__ ushort2 pk_bf16(float a, float b) {
    __hip_bfloat162 h = __float22bfloat162_rn(make_float2(a, b));
    return *(ushort2*)&h;
}

__device__ __forceinline__ float bflo(unsigned v) {
    union { unsigned u; float f; } c; c.u = v << 16; return c.f;
}
__device__ __forceinline__ float bfhi(unsigned v) {
    union { unsigned u; float f; } c; c.u = v & 0xffff0000u; return c.f;
}

// ---------------- kA1: wom2 repack (conv-weight bf16) ----------------
__global__ __launch_bounds__(256) void kA1_womprep(
    const float* __restrict__ offw, const float* __restrict__ modw,
    ushort_t* __restrict__ wom2) {
    const int tid = blockIdx.x * 256 + threadIdx.x;   // 36864
    const int kpart = tid & 31, n = (tid >> 5) & 31, kcg = tid >> 10;
    const int k = kcg * 32 + kpart;
    float v = 0.f;
    if (n < 18) v = offw[k * 18 + n];
    else if (n < 27) v = modw[k * 9 + (n - 18)];
    wom2[tid] = f2bf(v);
}

// ---------------- kA2: fused prep ----------------
// blocks 0..511     : offset/mod conv + bilinear metadata (reads fp32 x)
// blocks 512..1535  : x -> bf16 convert (8 float4 / thread)
// blocks 1536..2687 : wt2 repack
#define XSS 72   // padded channel stride (shorts)
__global__ __launch_bounds__(256) void kA2_prep(
    const float* __restrict__ x, const float* __restrict__ kern,
    const ushort_t* __restrict__ wom2,
    const float* __restrict__ offb, const float* __restrict__ modb,
    ushort_t* __restrict__ xbf, ushort_t* __restrict__ wt2,
    float4* __restrict__ metaw, int2* __restrict__ metai) {
    __shared__ ushort_t xs[3 * 130 * XSS];
    const int gid = blockIdx.x;
    const int t = threadIdx.x;

    if (gid >= 512) {
        const int g2 = gid - 512;
        if (g2 < 1024) {
            // x convert: 1024 blocks x 256 thr x 8 float4
#pragma unroll
            for (int i = 0; i < 8; ++i) {
                const int idx = (g2 * 256 + t) + i * (1024 * 256);
                float4 v = ((const float4*)x)[idx];
                ushort4 u;
                u.x = f2bf(v.x); u.y = f2bf(v.y); u.z = f2bf(v.z); u.w = f2bf(v.w);
                ((ushort4*)xbf)[idx] = u;
            }
        } else {
            // wt2: 1152 blocks, 294912 elems
            const int tid = (g2 - 1024) * 256 + t;
            const int kpart = tid & 31, n = (tid >> 5) & 255, kcg = tid >> 13;
            const int k = kcg * 32 + kpart;     // k = tap*128 + c
            wt2[tid] = f2bf(kern[k * 256 + n]);
        }
        return;
    }

    // ---- conv section: block per (b,h) ----
    float* Cs = (float*)xs;
    const int bid = gid;
    const int b = bid >> 7, h = bid & 127;
    const int lane = t & 63, wv = t >> 6;    // 4 waves
    const int ln = lane & 15, quad = lane >> 4;

    f32x4 acc[2][2];
#pragma unroll
    for (int i = 0; i < 2; ++i)
#pragma unroll
        for (int j = 0; j < 2; ++j) acc[i][j] = (f32x4){0.f, 0.f, 0.f, 0.f};

    for (int half = 0; half < 2; ++half) {
        // stage 3 rows x 128 px x 64 ch from fp32 x, convert inline
        for (int u = t; u < 768; u += 256) {
            const int r = u >> 8, rem = u & 255;
            const int xw = rem >> 1, sub = rem & 1;
            const int y = h + r - 1;
            ushort_t* dst = &xs[(r * 130 + xw + 1) * XSS + sub * 32];
            if ((unsigned)y < 128u) {
                const float* src = x + (((b * 128 + y) * 128 + xw) * 128) + half * 64 + sub * 32;
#pragma unroll
                for (int j = 0; j < 4; ++j) {
                    float4 va = *(const float4*)(src + j * 8);
                    float4 vb = *(const float4*)(src + j * 8 + 4);
                    u16x8 ov;
                    ov[0] = f2bf(va.x); ov[1] = f2bf(va.y);
                    ov[2] = f2bf(va.z); ov[3] = f2bf(va.w);
                    ov[4] = f2bf(vb.x); ov[5] = f2bf(vb.y);
                    ov[6] = f2bf(vb.z); ov[7] = f2bf(vb.w);
                    *(u16x8*)(dst + j * 8) = ov;
                }
            } else {
                const int4 z = make_int4(0, 0, 0, 0);
#pragma unroll
                for (int j = 0; j < 4; ++j) *(int4*)(dst + j * 8) = z;
            }
        }
        if (t < 48) {   // halo columns cc=0, cc=129
            const int r = t >> 4, side = (t >> 3) & 1, j = t & 7;
            *(int4*)&xs[(r * 130 + side * 129) * XSS + j * 8] = make_int4(0, 0, 0, 0);
        }
        __syncthreads();
#pragma unroll
        for (int tap = 0; tap < 9; ++tap) {
            const int ky = tap / 3, kx = tap % 3;
#pragma unroll
            for (int kc = 0; kc < 2; ++kc) {
                const int col = kc * 32 + quad * 8;
                const ushort_t* arow = &xs[(ky * 130 + kx) * XSS + col];
                bf16x8 a0 = *(const bf16x8*)(arow + (wv * 32 + ln) * XSS);
                bf16x8 a1 = *(const bf16x8*)(arow + (wv * 32 + 16 + ln) * XSS);
                const int kcg = tap * 4 + half * 2 + kc;
                const ushort_t* bp = wom2 + kcg * 1024 + quad * 8;
                bf16x8 b0 = *(const bf16x8*)(bp + ln * 32);
                bf16x8 b1 = *(const bf16x8*)(bp + (ln + 16) * 32);
                acc[0][0] = __builtin_amdgcn_mfma_f32_16x16x32_bf16(a0, b0, acc[0][0], 0, 0, 0);
                acc[0][1] = __builtin_amdgcn_mfma_f32_16x16x32_bf16(a0, b1, acc[0][1], 0, 0, 0);
                acc[1][0] = __builtin_amdgcn_mfma_f32_16x16x32_bf16(a1, b0, acc[1][0], 0, 0, 0);
                acc[1][1] = __builtin_amdgcn_mfma_f32_16x16x32_bf16(a1, b1, acc[1][1], 0, 0, 0);
            }
        }
        __syncthreads();
    }
#pragma unroll
    for (int mi = 0; mi < 2; ++mi)
#pragma unroll
        for (int nt = 0; nt < 2; ++nt)
#pragma unroll
            for (int r = 0; r < 4; ++r) {
                const int m = wv * 32 + mi * 16 + quad * 4 + r;
                const int n = nt * 16 + ln;
                if (n < 27) Cs[m * 32 + n] = acc[mi][nt][r];
            }
    __syncthreads();
    const int px = t >> 1;
    const int p = bid * 128 + px;
    for (int tap = (t & 1); tap < 9; tap += 2) {
        const float oy = Cs[px * 32 + 2 * tap] + offb[2 * tap];
        const float ox = Cs[px * 32 + 2 * tap + 1] + offb[2 * tap + 1];
        float md = Cs[px * 32 + 18 + tap] + modb[tap];
        md = 1.f / (1.f + __expf(-md));
        const float gy = fminf(fmaxf((float)(tap / 3 - 1) + oy, 0.f), 127.f);
        const float gx = fminf(fmaxf((float)(tap % 3 - 1) + ox, 0.f), 127.f);
        const float y0f = floorf(gy), x0f = floorf(gx);
        const int y0 = (int)y0f, x0 = (int)x0f;
        const int dy = (y0 < 127) ? 16384 : 0;
        const int dx = (x0 < 127) ? 128 : 0;
        const float wy1 = gy - y0f, wx1 = gx - x0f;
        const float wy0 = 1.f - wy1, wx0 = 1.f - wx1;
        metaw[p * 9 + tap] = make_float4(md * wy0 * wx0, md * wy0 * wx1,
                                         md * wy1 * wx0, md * wy1 * wx1);
        metai[p * 9 + tap] = make_int2((y0 * 128 + x0) * 128, dy + dx);
    }
}

// ---------------- K2: fused sample + modulate + GEMM ----------------
// 1024 blocks (64 px each), 512 thr / 8 waves. Wave tile 64m x 32n.
// bf16 gathers. Double-buffered XOR-swizzled LDS A tile.
__device__ __forceinline__ u16x8 lerp8(uint4 a, uint4 b, uint4 c, uint4 d, float4 w) {
    const unsigned* pa = (const unsigned*)&a;
    const unsigned* pb = (const unsigned*)&b;
    const unsigned* pc = (const unsigned*)&c;
    const unsigned* pd = (const unsigned*)&d;
    u16x8 r;
#pragma unroll
    for (int j = 0; j < 4; ++j) {
        float sl = w.x * bflo(pa[j]) + w.y * bflo(pb[j]) + w.z * bflo(pc[j]) + w.w * bflo(pd[j]);
        float sh = w.x * bfhi(pa[j]) + w.y * bfhi(pb[j]) + w.z * bfhi(pc[j]) + w.w * bfhi(pd[j]);
        ushort2 pk2 = pk_bf16(sl, sh);
        r[2 * j] = pk2.x; r[2 * j + 1] = pk2.y;
    }
    return r;
}

__device__ __forceinline__ void stage64(ushort_t* __restrict__ dst,
                                        const ushort_t* __restrict__ xb,
                                        int si, int cb, float4 w, int2 mi_) {
    const ushort_t* r00 = xb + mi_.x + cb * 16;
    const ushort_t* r01 = r00 + (mi_.y & 128);
    const ushort_t* r10 = r00 + (mi_.y & 16384);
    const ushort_t* r11 = r00 + mi_.y;
    uint4 u00a = *(const uint4*)r00, u00b = *(const uint4*)(r00 + 8);
    uint4 u01a = *(const uint4*)r01, u01b = *(const uint4*)(r01 + 8);
    uint4 u10a = *(const uint4*)r10, u10b = *(const uint4*)(r10 + 8);
    uint4 u11a = *(const uint4*)r11, u11b = *(const uint4*)(r11 + 8);
    const int sw = si & 15;
    *(u16x8*)&dst[si * 128 + (((cb * 2) ^ sw) << 3)]     = lerp8(u00a, u01a, u10a, u11a, w);
    *(u16x8*)&dst[si * 128 + (((cb * 2 + 1) ^ sw) << 3)] = lerp8(u00b, u01b, u10b, u11b, w);
}

__global__ __launch_bounds__(512, 4) void k2_main(
    const ushort_t* __restrict__ xbf, const ushort_t* __restrict__ wt2,
    const float4* __restrict__ metaw, const int2* __restrict__ metai,
    const float* __restrict__ bias, float* __restrict__ out) {
    __shared__ ushort_t As[2 * 8192];   // 32 KB: two 64x128 bf16 tiles, XOR-swizzled
    const int bid = blockIdx.x;
    const int b = bid >> 8;
    const int t = threadIdx.x;
    const int lane = t & 63, wv = t >> 6;      // 8 waves
    const int ln = lane & 15, quad = lane >> 4;
    const int ng = wv;                         // n-slice base = ng*32
    const int p0 = bid * 64;

    f32x4 acc[4][2];
#pragma unroll
    for (int i = 0; i < 4; ++i)
#pragma unroll
        for (int j = 0; j < 2; ++j) acc[i][j] = (f32x4){0.f, 0.f, 0.f, 0.f};

    const int si = t >> 3, cb = t & 7;         // 64 px x 8 ch-groups (16 ch)
    const int p = p0 + si;
    const ushort_t* xb = xbf + b * (1 << 21);

    float4 mw0 = metaw[p * 9];
    int2 mi0 = metai[p * 9];
    stage64(As, xb, si, cb, mw0, mi0);
    float4 mwN = metaw[p * 9 + 1];
    int2 miN = metai[p * 9 + 1];
    __syncthreads();

    for (int tap = 0; tap < 9; ++tap) {
        const ushort_t* buf = As + (tap & 1) * 8192;
#pragma unroll
        for (int kc = 0; kc < 4; ++kc) {
            const int chunk = kc * 4 + quad;
            bf16x8 a[4], bb[2];
#pragma unroll
            for (int mi2 = 0; mi2 < 4; ++mi2) {
                const int m = mi2 * 16 + ln;
                a[mi2] = *(const bf16x8*)&buf[m * 128 + ((chunk ^ ln) << 3)];
            }
            const int kcg = tap * 4 + kc;
#pragma unroll
            for (int nj = 0; nj < 2; ++nj) {
                const int n = ng * 32 + nj * 16 + ln;
                bb[nj] = *(const bf16x8*)&wt2[(kcg * 256 + n) * 32 + quad * 8];
            }
#pragma unroll
            for (int mi2 = 0; mi2 < 4; ++mi2)
#pragma unroll
                for (int nj = 0; nj < 2; ++nj)
                    acc[mi2][nj] = __builtin_amdgcn_mfma_f32_16x16x32_bf16(
                        a[mi2], bb[nj], acc[mi2][nj], 0, 0, 0);
        }
        if (tap < 8) {
            float4 mwP; int2 miP;
            if (tap < 7) { mwP = metaw[p * 9 + tap + 2]; miP = metai[p * 9 + tap + 2]; }
            stage64(As + ((tap + 1) & 1) * 8192, xb, si, cb, mwN, miN);
            mwN = mwP; miN = miP;
        }
        __syncthreads();
    }
#pragma unroll
    for (int mi2 = 0; mi2 < 4; ++mi2)
#pragma unroll
        for (int nj = 0; nj < 2; ++nj) {
            const int n = ng * 32 + nj * 16 + ln;
            const float bs = bias[n];
#pragma unroll
            for (int r = 0; r < 4; ++r) {
                const int m = mi2 * 16 + quad * 4 + r;
                out[(p0 + m) * 256 + n] = acc[mi2][nj][r] + bs;
            }
        }
}

extern "C" void kernel_launch(void* const* d_in, const int* in_sizes, int n_in,
                              void* d_out, int out_size, void* d_ws, size_t ws_size,
                              hipStream_t stream) {
    const float* x    = (const float*)d_in[0];
    const float* offw = (const float*)d_in[1];
    const float* offb = (const float*)d_in[2];
    const float* modw = (const float*)d_in[3];
    const float* modb = (const float*)d_in[4];
    const float* kern = (const float*)d_in[5];
    const float* bias = (const float*)d_in[6];
    float* out = (float*)d_out;

    char* ws = (char*)d_ws;
    ushort_t* xbf   = (ushort_t*)(ws);
    ushort_t* wt2   = (ushort_t*)(ws + 16777216);
    ushort_t* wom2  = (ushort_t*)(ws + 17367040);
    float4*   metaw = (float4*)(ws + 17440768);
    int2*     metai = (int2*)(ws + 26877952);

    kA1_womprep<<<144, 256, 0, stream>>>(offw, modw, wom2);
    kA2_prep<<<2688, 256, 0, stream>>>(x, kern, wom2, offb, modb, xbf, wt2, metaw, metai);
    k2_main<<<1024, 512, 0, stream>>>(xbf, wt2, metaw, metai, bias, out);
}